// Round 14
// baseline (318.430 us; speedup 1.0000x reference)
//
#include <hip/hip_runtime.h>

#define NB 8
#define NT 512
#define NS 1024
#define NV 32000
#define BT 4096
#define SQH 0.70710678118654752440f
#define ATTN_SCALE 11.313708498984761f

typedef __attribute__((ext_vector_type(8))) short bf16x8;
typedef __attribute__((ext_vector_type(4))) float f32x4;
typedef unsigned short u16_t;
typedef unsigned int u32_t;

#define MFMA16(a, b, c) __builtin_amdgcn_mfma_f32_16x16x32_bf16((a), (b), (c), 0, 0, 0)

typedef __attribute__((address_space(1))) const u32_t gas_u32;
typedef __attribute__((address_space(3))) u32_t las_u32;
__device__ __forceinline__ void gld_lds16(const u16_t* g, u16_t* l){
  __builtin_amdgcn_global_load_lds((gas_u32*)g, (las_u32*)l, 16, 0, 0);
}

__device__ __forceinline__ u16_t f2bf(float f){
  union { float f; u32_t i; } v; v.f = f;
  return (u16_t)((v.i + 0x7fffu + ((v.i >> 16) & 1u)) >> 16);
}

// ================= merged prep kernel: 1725 heterogeneous block-tasks =============
__global__ __launch_bounds__(256) void k_prep(
    const float* __restrict__ input_x, const float* __restrict__ enc_out,
    const float* __restrict__ enc_att, const float* __restrict__ W1,
    const float* __restrict__ b1, const float* __restrict__ convW,
    const float* __restrict__ W3,
    u16_t* __restrict__ Wt, u16_t* __restrict__ W3t, float* __restrict__ dl1v,
    u16_t* __restrict__ ybf, u16_t* __restrict__ eabf, u16_t* __restrict__ eoT){
  __shared__ __align__(16) char smem[33792];
  int tid = threadIdx.x, t = blockIdx.x;

  if(t < 320){
    float (*tile)[130] = (float(*)[130])smem;     // [ic][oc]
    const float* src = convW + (size_t)t * 8192;
    for(int i = tid; i < 8192; i += 256) tile[i >> 7][i & 127] = src[i];
    __syncthreads();
    u16_t* dst = Wt + (size_t)t * 8192;
    for(int i = tid; i < 8192; i += 256){
      int oc = i >> 6;
      int ic = (((i & 63) << 1) ^ ((oc & 7) << 4)) >> 1;
      dst[i] = f2bf(tile[ic][oc]);
    }
  } else if(t < 448){
    int blk = t - 320;
    int b = blk >> 4, s0 = (blk & 15) << 6;
    float (*tile)[65] = (float(*)[65])smem;
    const float* easrc = enc_att + ((size_t)b * NS + s0) * 64;
    u16_t* eadst = eabf + ((size_t)b * NS + s0) * 64;
    for(int i = tid; i < 512; i += 256){
      float4 f0 = *(const float4*)(easrc + i * 8);
      float4 f1 = *(const float4*)(easrc + i * 8 + 4);
      union { u32_t u[4]; bf16x8 v; } pk;
      pk.u[0] = f2bf(f0.x) | ((u32_t)f2bf(f0.y) << 16);
      pk.u[1] = f2bf(f0.z) | ((u32_t)f2bf(f0.w) << 16);
      pk.u[2] = f2bf(f1.x) | ((u32_t)f2bf(f1.y) << 16);
      pk.u[3] = f2bf(f1.z) | ((u32_t)f2bf(f1.w) << 16);
      *(bf16x8*)(eadst + i * 8) = pk.v;
    }
    const float* eosrc = enc_out + ((size_t)b * NS + s0) * 64;
    for(int i = tid; i < 1024; i += 256){
      int s = i >> 4, e0 = (i & 15) * 4;
      float4 f = *(const float4*)(eosrc + s * 64 + e0);
      tile[s][e0] = f.x; tile[s][e0 + 1] = f.y; tile[s][e0 + 2] = f.z; tile[s][e0 + 3] = f.w;
    }
    __syncthreads();
    for(int i = tid; i < 512; i += 256){
      int e = i >> 3, sc = (i & 7) * 8;
      union { u32_t u[4]; bf16x8 v; } pk;
      #pragma unroll
      for(int j = 0; j < 4; j++){
        float lo = tile[sc + 2 * j][e], hi = tile[sc + 2 * j + 1][e];
        pk.u[j] = f2bf(lo) | ((u32_t)f2bf(hi) << 16);
      }
      *(bf16x8*)(eoT + ((size_t)b * 64 + e) * NS + s0 + sc) = pk.v;
    }
  } else if(t < 573){
    u32_t (*lt)[33] = (u32_t(*)[33])smem;
    int v0 = (t - 448) * 256;
    for(int it = 0; it < 8; it++){
      int u = it * 256 + tid;
      int rp = u >> 6;
      int c4 = (u & 63) * 4;
      const float* r0p = W3 + (size_t)(2 * rp) * NV + v0 + c4;
      float4 a4 = *(const float4*)r0p;
      float4 b4 = *(const float4*)(r0p + NV);
      lt[c4 + 0][rp] = f2bf(a4.x) | ((u32_t)f2bf(b4.x) << 16);
      lt[c4 + 1][rp] = f2bf(a4.y) | ((u32_t)f2bf(b4.y) << 16);
      lt[c4 + 2][rp] = f2bf(a4.z) | ((u32_t)f2bf(b4.z) << 16);
      lt[c4 + 3][rp] = f2bf(a4.w) | ((u32_t)f2bf(b4.w) << 16);
    }
    __syncthreads();
    u32_t* dst = (u32_t*)(W3t + (size_t)v0 * 64);
    for(int it = 0; it < 32; it++){
      int idx = it * 256 + tid;
      dst[idx] = lt[idx >> 5][idx & 31];
    }
  } else if(t < 701){
    int i = (t - 573) * 256 + tid;
    int b = i >> 12, rem = i & 4095;
    int pr = rem >> 6, c = rem & 63;
    int row = pr < 31 ? pr : pr + 512;
    ybf[((size_t)b * 576 + row) * 64 + c] = 0;
  } else {
    int r0 = (t - 701) * 4;
    float (*xs)[64] = (float(*)[64])smem;
    xs[tid >> 6][tid & 63] = input_x[(size_t)r0 * 64 + tid];
    __syncthreads();
    int h = tid & 63, rr = tid >> 6;
    float acc = b1[h];
    #pragma unroll 16
    for(int e = 0; e < 64; e++) acc = fmaf(xs[rr][e], W1[e * 64 + h], acc);
    float v = fmaxf(acc, 0.f);
    int row = r0 + rr;
    dl1v[(size_t)row * 64 + h] = v;
    ybf[((size_t)(row >> 9) * 576 + (row & 511) + 31) * 64 + h] = f2bf(v);
  }
}

// ======== conv: implicit GEMM, 2-way kw split (10 partials, 544 active blocks) ====
__global__ __launch_bounds__(256) void k_conv(const u16_t* __restrict__ ybf,
                                              const u16_t* __restrict__ Wt,
                                              float* __restrict__ part){
  int mt = blockIdx.x;       // 0..63
  int khh = blockIdx.y;      // 0..9 : kh = khh>>1, kw-half = khh&1
  int kh = khh >> 1, half = khh & 1;
  int b = mt >> 3, t0 = (mt & 7) << 6;
  int bp = b + kh - 2;
  if(bp < 0 || bp >= NB) return;
  __shared__ u16_t strip[95 * 72];
  __shared__ u16_t wtile[2][8192];
  int tid = threadIdx.x;
  int lane = tid & 63, wid = tid >> 6;
  int l15 = lane & 15, lgp = lane >> 4;

  const u16_t* ysrc = ybf + ((size_t)bp * 576 + t0 + half * 32) * 64;
  for(int li = tid; li < 760; li += 256)
    *(bf16x8*)(strip + (li >> 3) * 72 + (li & 7) * 8) = *(const bf16x8*)(ysrc + li * 8);

  const u16_t* wsrc = Wt + ((size_t)kh * 64 + half * 32) * 8192;
  {
    const u16_t* g = wsrc + tid * 8;
    #pragma unroll
    for(int j = 0; j < 4; j++)
      gld_lds16(g + j * 2048, &wtile[0][j * 2048 + wid * 512]);
  }
  __syncthreads();

  int wm = wid >> 1, wn = wid & 1;
  f32x4 acc[2][4];
  #pragma unroll
  for(int m = 0; m < 2; m++)
    #pragma unroll
    for(int n = 0; n < 4; n++) acc[m][n] = (f32x4){0.f, 0.f, 0.f, 0.f};
  int arow0 = wm * 32 + l15;

  int qoff[2][4];
  #pragma unroll
  for(int ks = 0; ks < 2; ks++)
    #pragma unroll
    for(int nf = 0; nf < 4; nf++){
      int oc = wn * 64 + nf * 16 + l15;
      int byte = (oc << 7) | (((ks << 6) | (lgp << 4)) ^ ((oc & 7) << 4));
      qoff[ks][nf] = byte >> 1;
    }

  for(int kw = 0; kw < 32; kw++){
    int cur = kw & 1;
    if(kw < 31){
      const u16_t* g = wsrc + (size_t)(kw + 1) * 8192 + tid * 8;
      #pragma unroll
      for(int j = 0; j < 4; j++)
        gld_lds16(g + j * 2048, &wtile[cur ^ 1][j * 2048 + wid * 512]);
      asm volatile("s_waitcnt vmcnt(4)" ::: "memory");
    } else {
      asm volatile("s_waitcnt vmcnt(0)" ::: "memory");
    }
    __builtin_amdgcn_s_barrier();
    const u16_t* wt = wtile[cur];
    #pragma unroll
    for(int ks = 0; ks < 2; ks++){
      bf16x8 a0 = *(const bf16x8*)(strip + (arow0 + kw) * 72 + ks * 32 + lgp * 8);
      bf16x8 a1 = *(const bf16x8*)(strip + (arow0 + 16 + kw) * 72 + ks * 32 + lgp * 8);
      bf16x8 q0 = *(const bf16x8*)(wt + qoff[ks][0]);
      bf16x8 q1 = *(const bf16x8*)(wt + qoff[ks][1]);
      bf16x8 q2 = *(const bf16x8*)(wt + qoff[ks][2]);
      bf16x8 q3 = *(const bf16x8*)(wt + qoff[ks][3]);
      acc[0][0] = MFMA16(a0, q0, acc[0][0]);
      acc[0][1] = MFMA16(a0, q1, acc[0][1]);
      acc[0][2] = MFMA16(a0, q2, acc[0][2]);
      acc[0][3] = MFMA16(a0, q3, acc[0][3]);
      acc[1][0] = MFMA16(a1, q0, acc[1][0]);
      acc[1][1] = MFMA16(a1, q1, acc[1][1]);
      acc[1][2] = MFMA16(a1, q2, acc[1][2]);
      acc[1][3] = MFMA16(a1, q3, acc[1][3]);
    }
    asm volatile("s_waitcnt lgkmcnt(0)" ::: "memory");
    __builtin_amdgcn_s_barrier();
  }

  float* dst = part + ((size_t)khh * BT + (size_t)mt * 64) * 128;
  #pragma unroll
  for(int mf = 0; mf < 2; mf++)
    #pragma unroll
    for(int nf = 0; nf < 4; nf++)
      #pragma unroll
      for(int r = 0; r < 4; r++){
        int row = wm * 32 + mf * 16 + lgp * 4 + r;
        int col = wn * 64 + nf * 16 + l15;
        dst[row * 128 + col] = acc[mf][nf][r];
      }
}

// ====== fused GLU + attention (8 rows / WG, 512 blocks) + w2 tail on layer 2 ======
__global__ __launch_bounds__(256) void k_attn(const float* __restrict__ part,
    const float* __restrict__ convb, const float* __restrict__ ycur,
    const u16_t* __restrict__ eabf, const u16_t* __restrict__ eoT,
    const float* __restrict__ Wce, const float* __restrict__ bce,
    const float* __restrict__ Wec, const float* __restrict__ bec,
    float* __restrict__ ynext, u16_t* __restrict__ ybf,
    const float* __restrict__ dl1v, const float* __restrict__ W2,
    const float* __restrict__ b2, u16_t* __restrict__ y2bf,
    float* __restrict__ esum, int L){
  int row0 = blockIdx.x << 3;      // 8 rows per block, 512 blocks
  int b = row0 >> 9;
  int tid = threadIdx.x;
  int lane = tid & 63, w = tid >> 6;
  int l15 = lane & 15, lgp = lane >> 4;

  __shared__ float yml[8][68];
  __shared__ float pgS[8][68];
  __shared__ u16_t pgb[16][72];    // rows 8..15 zeroed (q>=8 lanes carry benign garbage)
  __shared__ float aof[4][64][17];
  __shared__ float aosm[8][68];
  __shared__ float reds[4][16];
  __shared__ float invt[8];

  // zero pgb rows 8..15 (cols 0..63 are all that qpg reads)
  for(int i = tid; i < 512; i += 256) pgb[8 + (i >> 6)][i & 63] = 0;

  // phase 0: GLU + residual (10 kw-split partials)
  for(int i = tid; i < 512; i += 256){
    int r = i >> 6, h = i & 63;
    int grow = row0 + r;
    float ca = convb[h], cb = convb[64 + h];
    #pragma unroll
    for(int pp = 0; pp < 10; pp++){
      int bpp = b + (pp >> 1) - 2;
      if(bpp >= 0 && bpp < NB){
        const float* p = part + ((size_t)pp * BT + grow) * 128;
        ca += p[h]; cb += p[64 + h];
      }
    }
    float sig = 1.f / (1.f + __expf(-cb));
    yml[r][h] = (ca * sig + ycur[(size_t)grow * 64 + h]) * SQH;
  }
  __syncthreads();
  // phase 0b: pg logits = yml @ Wce + bce (2 rows per 64-thread group)
  {
    int h = tid & 63, g = tid >> 6;
    float a0 = bce[h], a1 = a0;
    #pragma unroll 16
    for(int e = 0; e < 64; e++){
      float wv = Wce[e * 64 + h];
      a0 = fmaf(yml[g * 2 + 0][e], wv, a0);
      a1 = fmaf(yml[g * 2 + 1][e], wv, a1);
    }
    pgS[g * 2 + 0][h] = a0; pgS[g * 2 + 1][h] = a1;
  }
  __syncthreads();
  // phase 1: softmax over 64, normalized pg -> bf16 (8 rows, one pass)
  {
    int r = tid >> 5, j = tid & 31;
    float v1 = __expf(pgS[r][j]), v2 = __expf(pgS[r][j + 32]);
    float s = v1 + v2;
    s += __shfl_xor(s, 1); s += __shfl_xor(s, 2); s += __shfl_xor(s, 4);
    s += __shfl_xor(s, 8); s += __shfl_xor(s, 16);
    float inv = 1.f / s;
    pgb[r][j] = f2bf(v1 * inv); pgb[r][j + 32] = f2bf(v2 * inv);
  }
  __syncthreads();

  // phase 2: per-wave 256-s slice: S^T = mfma(ea, pg); P = exp; AV = mfma(eoT, P^T)
  bf16x8 qpg0 = *(const bf16x8*)&pgb[l15][lgp * 8];
  bf16x8 qpg1 = *(const bf16x8*)&pgb[l15][32 + lgp * 8];
  float sumacc = 0.f;
  f32x4 ao[4];
  #pragma unroll
  for(int et = 0; et < 4; et++) ao[et] = (f32x4){0.f, 0.f, 0.f, 0.f};
  const u16_t* eab = eabf + ((size_t)b * NS + w * 256) * 64;
  const u16_t* eob = eoT + (size_t)b * 64 * NS + w * 256;
  for(int sc = 0; sc < 8; sc++){
    int sb = sc * 32;
    const u16_t* ar = eab + (size_t)(sb + l15) * 64 + lgp * 8;
    bf16x8 a00 = *(const bf16x8*)ar;
    bf16x8 a01 = *(const bf16x8*)(ar + 32);
    bf16x8 a10 = *(const bf16x8*)(ar + 1024);
    bf16x8 a11 = *(const bf16x8*)(ar + 1024 + 32);
    f32x4 s0 = {0.f, 0.f, 0.f, 0.f}, s1 = {0.f, 0.f, 0.f, 0.f};
    s0 = MFMA16(a00, qpg0, s0); s0 = MFMA16(a01, qpg1, s0);
    s1 = MFMA16(a10, qpg0, s1); s1 = MFMA16(a11, qpg1, s1);
    float p00 = __expf(s0[0]), p01 = __expf(s0[1]), p02 = __expf(s0[2]), p03 = __expf(s0[3]);
    float p10 = __expf(s1[0]), p11 = __expf(s1[1]), p12 = __expf(s1[2]), p13 = __expf(s1[3]);
    sumacc += (p00 + p01) + (p02 + p03) + (p10 + p11) + (p12 + p13);
    u32_t A0, B0, A1, B1;
    asm("v_cvt_pk_bf16_f32 %0, %1, %2" : "=v"(A0) : "v"(p00), "v"(p01));
    asm("v_cvt_pk_bf16_f32 %0, %1, %2" : "=v"(B0) : "v"(p02), "v"(p03));
    asm("v_cvt_pk_bf16_f32 %0, %1, %2" : "=v"(A1) : "v"(p10), "v"(p11));
    asm("v_cvt_pk_bf16_f32 %0, %1, %2" : "=v"(B1) : "v"(p12), "v"(p13));
    int src0 = l15 + ((lgp & 1) << 5);
    int src1 = src0 + 16;
    u32_t w0a = (u32_t)__shfl((int)A0, src0, 64), w0b = (u32_t)__shfl((int)A1, src0, 64);
    u32_t w1a = (u32_t)__shfl((int)B0, src0, 64), w1b = (u32_t)__shfl((int)B1, src0, 64);
    u32_t w2a = (u32_t)__shfl((int)A0, src1, 64), w2b = (u32_t)__shfl((int)A1, src1, 64);
    u32_t w3a = (u32_t)__shfl((int)B0, src1, 64), w3b = (u32_t)__shfl((int)B1, src1, 64);
    bool hi = lgp >= 2;
    union { u32_t u[4]; bf16x8 v; } bav;
    bav.u[0] = hi ? w0b : w0a; bav.u[1] = hi ? w1b : w1a;
    bav.u[2] = hi ? w2b : w2a; bav.u[3] = hi ? w3b : w3a;
    #pragma unroll
    for(int et = 0; et < 4; et++){
      const u16_t* er = eob + (size_t)(et * 16 + l15) * NS + sb + lgp * 8;
      bf16x8 ae = *(const bf16x8*)er;
      ao[et] = MFMA16(ae, bav.v, ao[et]);
    }
  }
  sumacc += __shfl_xor(sumacc, 16);
  sumacc += __shfl_xor(sumacc, 32);
  if(lane < 16) reds[w][l15] = sumacc;
  #pragma unroll
  for(int et = 0; et < 4; et++)
    #pragma unroll
    for(int r = 0; r < 4; r++)
      aof[w][et * 16 + lgp * 4 + r][l15] = ao[et][r];
  __syncthreads();
  if(tid < 8) invt[tid] = ATTN_SCALE / (reds[0][tid] + reds[1][tid] + reds[2][tid] + reds[3][tid]);
  __syncthreads();
  // phase 3: sum wave partials, scale, transpose to [t][e] (t < 8)
  for(int i = tid; i < 512; i += 256){
    int e = i >> 3, t = i & 7;
    aosm[t][e] = (aof[0][e][t] + aof[1][e][t] + aof[2][e][t] + aof[3][e][t]) * invt[t];
  }
  __syncthreads();
  // phase 4: y logits = aosm @ Wec + bec
  {
    int h = tid & 63, g = tid >> 6;
    float a0 = bec[h], a1 = a0;
    #pragma unroll 16
    for(int e = 0; e < 64; e++){
      float wv = Wec[e * 64 + h];
      a0 = fmaf(aosm[g * 2 + 0][e], wv, a0);
      a1 = fmaf(aosm[g * 2 + 1][e], wv, a1);
    }
    pgS[g * 2 + 0][h] = a0; pgS[g * 2 + 1][h] = a1;
  }
  __syncthreads();
  // phase 5: softmax over 64; store (L<2) or stash for w2 tail (L==2)
  {
    int r = tid >> 5, j = tid & 31;
    float v1 = __expf(pgS[r][j]), v2 = __expf(pgS[r][j + 32]);
    float s = v1 + v2;
    s += __shfl_xor(s, 1); s += __shfl_xor(s, 2); s += __shfl_xor(s, 4);
    s += __shfl_xor(s, 8); s += __shfl_xor(s, 16);
    float inv = 1.f / s;
    float o1 = v1 * inv, o2 = v2 * inv;
    if(L < 2){
      int grow = row0 + r;
      ynext[(size_t)grow * 64 + j] = o1;
      ynext[(size_t)grow * 64 + j + 32] = o2;
      size_t yb = ((size_t)(grow >> 9) * 576 + (grow & 511) + 31) * 64;
      ybf[yb + j] = f2bf(o1);
      ybf[yb + j + 32] = f2bf(o2);
    } else {
      yml[r][j] = o1;
      yml[r][j + 32] = o2;
    }
  }
  if(L == 2){
    __syncthreads();
    // w2 tail: x = (y + dl1)*SQ ; y2 = relu(x@W2+b2) -> bf16 ; zero esum
    for(int i = tid; i < 512; i += 256){
      int r = i >> 6, h = i & 63;
      pgS[r][h] = (yml[r][h] + dl1v[(size_t)(row0 + r) * 64 + h]) * SQH;
    }
    __syncthreads();
    int h = tid & 63, g = tid >> 6;
    float a0 = b2[h], a1 = a0;
    #pragma unroll 16
    for(int e = 0; e < 64; e++){
      float wv = W2[e * 64 + h];
      a0 = fmaf(pgS[g * 2 + 0][e], wv, a0);
      a1 = fmaf(pgS[g * 2 + 1][e], wv, a1);
    }
    y2bf[(size_t)(row0 + g * 2 + 0) * 64 + h] = f2bf(fmaxf(a0, 0.f));
    y2bf[(size_t)(row0 + g * 2 + 1) * 64 + h] = f2bf(fmaxf(a1, 0.f));
    if(tid < 8) esum[row0 + tid] = 0.f;
  }
}

// ================= V-GEMM pass A (M-tile 64) =================
__global__ __launch_bounds__(256) void k_va(const u16_t* __restrict__ y2bf,
    const u16_t* __restrict__ W3t, const float* __restrict__ b3, float* __restrict__ esum){
  int m0 = blockIdx.x << 6, ns = blockIdx.y;
  int tid = threadIdx.x, lane = tid & 63, w = tid >> 6;
  int l15 = lane & 15, lgp = lane >> 4;
  bf16x8 a[4][2];
  #pragma unroll
  for(int mg = 0; mg < 4; mg++){
    const u16_t* ar = y2bf + ((size_t)(m0 + mg * 16 + l15) << 6) + lgp * 8;
    a[mg][0] = *(const bf16x8*)ar;
    a[mg][1] = *(const bf16x8*)(ar + 32);
  }
  float sums[4][4];
  #pragma unroll
  for(int mg = 0; mg < 4; mg++)
    #pragma unroll
    for(int r = 0; r < 4; r++) sums[mg][r] = 0.f;

  int nb0 = ns * 1600 + w * 400;
  for(int fi = 0; fi < 25; fi++){
    int n = nb0 + fi * 16 + l15;
    const u16_t* bp2 = W3t + ((size_t)n << 6) + lgp * 8;
    bf16x8 q0 = *(const bf16x8*)bp2;
    bf16x8 q1 = *(const bf16x8*)(bp2 + 32);
    float bias = b3[n];
    #pragma unroll
    for(int mg = 0; mg < 4; mg++){
      f32x4 acc = {0.f, 0.f, 0.f, 0.f};
      acc = MFMA16(a[mg][0], q0, acc);
      acc = MFMA16(a[mg][1], q1, acc);
      #pragma unroll
      for(int r = 0; r < 4; r++){
        float z = fmaxf(acc[r] + bias, 0.f);
        sums[mg][r] += __expf(z);
      }
    }
  }
  #pragma unroll
  for(int mg = 0; mg < 4; mg++)
    #pragma unroll
    for(int r = 0; r < 4; r++){
      float v = sums[mg][r];
      v += __shfl_xor(v, 1); v += __shfl_xor(v, 2);
      v += __shfl_xor(v, 4); v += __shfl_xor(v, 8);
      if(l15 == 0) atomicAdd(&esum[m0 + mg * 16 + lgp * 4 + r], v);
    }
}

// ====== V-GEMM pass B (M-tile 64, coalesced obuf stores, nontemporal writes) ======
__global__ __launch_bounds__(256) void k_vb(const u16_t* __restrict__ y2bf,
    const u16_t* __restrict__ W3t, const float* __restrict__ b3,
    const float* __restrict__ esum, float* __restrict__ out){
  int m0 = blockIdx.x << 6, ns = blockIdx.y;
  int tid = threadIdx.x, lane = tid & 63, w = tid >> 6;
  int l15 = lane & 15, lgp = lane >> 4;
  __shared__ float obuf[64][84];
  bf16x8 a[4][2];
  #pragma unroll
  for(int mg = 0; mg < 4; mg++){
    const u16_t* ar = y2bf + ((size_t)(m0 + mg * 16 + l15) << 6) + lgp * 8;
    a[mg][0] = *(const bf16x8*)ar;
    a[mg][1] = *(const bf16x8*)(ar + 32);
  }
  float invs[4][4];
  #pragma unroll
  for(int mg = 0; mg < 4; mg++)
    #pragma unroll
    for(int r = 0; r < 4; r++) invs[mg][r] = 1.f / esum[m0 + mg * 16 + lgp * 4 + r];

  int cb0 = ns * 1600;
  for(int si = 0; si < 25; si++){
    int cb = cb0 + si * 64;
    int n = cb + w * 16 + l15;
    const u16_t* bp2 = W3t + ((size_t)n << 6) + lgp * 8;
    bf16x8 q0 = *(const bf16x8*)bp2;
    bf16x8 q1 = *(const bf16x8*)(bp2 + 32);
    float bias = b3[n];
    #pragma unroll
    for(int mg = 0; mg < 4; mg++){
      f32x4 acc = {0.f, 0.f, 0.f, 0.f};
      acc = MFMA16(a[mg][0], q0, acc);
      acc = MFMA16(a[mg][1], q1, acc);
      #pragma unroll
      for(int r = 0; r < 4; r++){
        float z = fmaxf(acc[r] + bias, 0.f);
        obuf[mg * 16 + lgp * 4 + r][w * 16 + l15] = __expf(z) * invs[mg][r];
      }
    }
    __syncthreads();
    #pragma unroll
    for(int p = 0; p < 4; p++){
      int row = p * 16 + (tid >> 4);
      f32x4 v = *(const f32x4*)&obuf[row][(tid & 15) * 4];
      __builtin_nontemporal_store(v, (f32x4*)&out[(size_t)(m0 + row) * NV + cb + (tid & 15) * 4]);
    }
    __syncthreads();
  }
}

extern "C" void kernel_launch(void* const* d_in, const int* in_sizes, int n_in,
                              void* d_out, int out_size, void* d_ws, size_t ws_size,
                              hipStream_t stream){
  const float* input_x = (const float*)d_in[0];
  const float* enc_out = (const float*)d_in[1];
  const float* enc_att = (const float*)d_in[2];
  const float* W1    = (const float*)d_in[3];
  const float* b1    = (const float*)d_in[4];
  const float* convW = (const float*)d_in[5];
  const float* convb = (const float*)d_in[6];
  const float* Wce   = (const float*)d_in[7];
  const float* bce   = (const float*)d_in[8];
  const float* Wec   = (const float*)d_in[9];
  const float* bec   = (const float*)d_in[10];
  const float* W2    = (const float*)d_in[11];
  const float* b2    = (const float*)d_in[12];
  const float* W3    = (const float*)d_in[13];
  const float* b3    = (const float*)d_in[14];

  char* ws = (char*)d_ws;
  u16_t* Wt    = (u16_t*)(ws);                 // 5,242,880 B
  u16_t* W3t   = (u16_t*)(ws + 5242880);       // 4,096,000 B
  float* dl1v  = (float*)(ws + 9338880);       // 1,048,576 B
  float* yB    = (float*)(ws + 10387456);      // 1,048,576 B
  u16_t* ybf   = (u16_t*)(ws + 11436032);      //   589,824 B
  float* part  = (float*)(ws + 12025856);      // 20,971,520 B (10 partials)
  u16_t* y2bf  = (u16_t*)(ws + 32997376);      //   524,288 B
  float* esum  = (float*)(ws + 33521664);      //    16,384 B
  u16_t* eabf  = (u16_t*)(ws + 33538048);      // 1,048,576 B
  u16_t* eoT   = (u16_t*)(ws + 34586624);      // 1,048,576 B
  float* outp  = (float*)d_out;

  k_prep<<<dim3(1725), dim3(256), 0, stream>>>(input_x, enc_out, enc_att, W1, b1,
                                               convW, W3, Wt, W3t, dl1v, ybf, eabf, eoT);

  const float* ycur = dl1v;
  for(int it = 0; it < 3; it++){
    k_conv<<<dim3(64, 10), dim3(256), 0, stream>>>(ybf, Wt, part);
    k_attn<<<dim3(512), dim3(256), 0, stream>>>(part, convb, ycur, eabf, eoT,
                                                Wce, bce, Wec, bec, yB, ybf,
                                                dl1v, W2, b2, y2bf, esum, it);
    ycur = yB;
  }

  k_va<<<dim3(64, 20), dim3(256), 0, stream>>>(y2bf, W3t, b3, esum);
  k_vb<<<dim3(64, 20), dim3(256), 0, stream>>>(y2bf, W3t, b3, esum, outp);
}

// Round 15
// 311.227 us; speedup vs baseline: 1.0231x; 1.0231x over previous
//
#include <hip/hip_runtime.h>

#define NB 8
#define NT 512
#define NS 1024
#define NV 32000
#define BT 4096
#define SQH 0.70710678118654752440f
#define ATTN_SCALE 11.313708498984761f

typedef __attribute__((ext_vector_type(8))) short bf16x8;
typedef __attribute__((ext_vector_type(4))) float f32x4;
typedef unsigned short u16_t;
typedef unsigned int u32_t;

#define MFMA16(a, b, c) __builtin_amdgcn_mfma_f32_16x16x32_bf16((a), (b), (c), 0, 0, 0)

typedef __attribute__((address_space(1))) const u32_t gas_u32;
typedef __attribute__((address_space(3))) u32_t las_u32;
__device__ __forceinline__ void gld_lds16(const u16_t* g, u16_t* l){
  __builtin_amdgcn_global_load_lds((gas_u32*)g, (las_u32*)l, 16, 0, 0);
}

__device__ __forceinline__ u16_t f2bf(float f){
  union { float f; u32_t i; } v; v.f = f;
  return (u16_t)((v.i + 0x7fffu + ((v.i >> 16) & 1u)) >> 16);
}

// ================= merged prep kernel: 1725 heterogeneous block-tasks =============
__global__ __launch_bounds__(256) void k_prep(
    const float* __restrict__ input_x, const float* __restrict__ enc_out,
    const float* __restrict__ enc_att, const float* __restrict__ W1,
    const float* __restrict__ b1, const float* __restrict__ convW,
    const float* __restrict__ W3,
    u16_t* __restrict__ Wt, u16_t* __restrict__ W3t, float* __restrict__ dl1v,
    u16_t* __restrict__ ybf, u16_t* __restrict__ eabf, u16_t* __restrict__ eoT){
  __shared__ __align__(16) char smem[33792];
  int tid = threadIdx.x, t = blockIdx.x;

  if(t < 320){
    float (*tile)[130] = (float(*)[130])smem;     // [ic][oc]
    const float* src = convW + (size_t)t * 8192;
    for(int i = tid; i < 8192; i += 256) tile[i >> 7][i & 127] = src[i];
    __syncthreads();
    u16_t* dst = Wt + (size_t)t * 8192;
    for(int i = tid; i < 8192; i += 256){
      int oc = i >> 6;
      int ic = (((i & 63) << 1) ^ ((oc & 7) << 4)) >> 1;
      dst[i] = f2bf(tile[ic][oc]);
    }
  } else if(t < 448){
    int blk = t - 320;
    int b = blk >> 4, s0 = (blk & 15) << 6;
    float (*tile)[65] = (float(*)[65])smem;
    const float* easrc = enc_att + ((size_t)b * NS + s0) * 64;
    u16_t* eadst = eabf + ((size_t)b * NS + s0) * 64;
    for(int i = tid; i < 512; i += 256){
      float4 f0 = *(const float4*)(easrc + i * 8);
      float4 f1 = *(const float4*)(easrc + i * 8 + 4);
      union { u32_t u[4]; bf16x8 v; } pk;
      pk.u[0] = f2bf(f0.x) | ((u32_t)f2bf(f0.y) << 16);
      pk.u[1] = f2bf(f0.z) | ((u32_t)f2bf(f0.w) << 16);
      pk.u[2] = f2bf(f1.x) | ((u32_t)f2bf(f1.y) << 16);
      pk.u[3] = f2bf(f1.z) | ((u32_t)f2bf(f1.w) << 16);
      *(bf16x8*)(eadst + i * 8) = pk.v;
    }
    const float* eosrc = enc_out + ((size_t)b * NS + s0) * 64;
    for(int i = tid; i < 1024; i += 256){
      int s = i >> 4, e0 = (i & 15) * 4;
      float4 f = *(const float4*)(eosrc + s * 64 + e0);
      tile[s][e0] = f.x; tile[s][e0 + 1] = f.y; tile[s][e0 + 2] = f.z; tile[s][e0 + 3] = f.w;
    }
    __syncthreads();
    for(int i = tid; i < 512; i += 256){
      int e = i >> 3, sc = (i & 7) * 8;
      union { u32_t u[4]; bf16x8 v; } pk;
      #pragma unroll
      for(int j = 0; j < 4; j++){
        float lo = tile[sc + 2 * j][e], hi = tile[sc + 2 * j + 1][e];
        pk.u[j] = f2bf(lo) | ((u32_t)f2bf(hi) << 16);
      }
      *(bf16x8*)(eoT + ((size_t)b * 64 + e) * NS + s0 + sc) = pk.v;
    }
  } else if(t < 573){
    u32_t (*lt)[33] = (u32_t(*)[33])smem;
    int v0 = (t - 448) * 256;
    for(int it = 0; it < 8; it++){
      int u = it * 256 + tid;
      int rp = u >> 6;
      int c4 = (u & 63) * 4;
      const float* r0p = W3 + (size_t)(2 * rp) * NV + v0 + c4;
      float4 a4 = *(const float4*)r0p;
      float4 b4 = *(const float4*)(r0p + NV);
      lt[c4 + 0][rp] = f2bf(a4.x) | ((u32_t)f2bf(b4.x) << 16);
      lt[c4 + 1][rp] = f2bf(a4.y) | ((u32_t)f2bf(b4.y) << 16);
      lt[c4 + 2][rp] = f2bf(a4.z) | ((u32_t)f2bf(b4.z) << 16);
      lt[c4 + 3][rp] = f2bf(a4.w) | ((u32_t)f2bf(b4.w) << 16);
    }
    __syncthreads();
    u32_t* dst = (u32_t*)(W3t + (size_t)v0 * 64);
    for(int it = 0; it < 32; it++){
      int idx = it * 256 + tid;
      dst[idx] = lt[idx >> 5][idx & 31];
    }
  } else if(t < 701){
    int i = (t - 573) * 256 + tid;
    int b = i >> 12, rem = i & 4095;
    int pr = rem >> 6, c = rem & 63;
    int row = pr < 31 ? pr : pr + 512;
    ybf[((size_t)b * 576 + row) * 64 + c] = 0;
  } else {
    int r0 = (t - 701) * 4;
    float (*xs)[64] = (float(*)[64])smem;
    xs[tid >> 6][tid & 63] = input_x[(size_t)r0 * 64 + tid];
    __syncthreads();
    int h = tid & 63, rr = tid >> 6;
    float acc = b1[h];
    #pragma unroll 16
    for(int e = 0; e < 64; e++) acc = fmaf(xs[rr][e], W1[e * 64 + h], acc);
    float v = fmaxf(acc, 0.f);
    int row = r0 + rr;
    dl1v[(size_t)row * 64 + h] = v;
    ybf[((size_t)(row >> 9) * 576 + (row & 511) + 31) * 64 + h] = f2bf(v);
  }
}

// ======== conv: implicit GEMM, 2-way kw split (10 partials, 544 active blocks) ====
__global__ __launch_bounds__(256) void k_conv(const u16_t* __restrict__ ybf,
                                              const u16_t* __restrict__ Wt,
                                              float* __restrict__ part){
  int mt = blockIdx.x;       // 0..63
  int khh = blockIdx.y;      // 0..9 : kh = khh>>1, kw-half = khh&1
  int kh = khh >> 1, half = khh & 1;
  int b = mt >> 3, t0 = (mt & 7) << 6;
  int bp = b + kh - 2;
  if(bp < 0 || bp >= NB) return;
  __shared__ u16_t strip[95 * 72];
  __shared__ u16_t wtile[2][8192];
  int tid = threadIdx.x;
  int lane = tid & 63, wid = tid >> 6;
  int l15 = lane & 15, lgp = lane >> 4;

  const u16_t* ysrc = ybf + ((size_t)bp * 576 + t0 + half * 32) * 64;
  for(int li = tid; li < 760; li += 256)
    *(bf16x8*)(strip + (li >> 3) * 72 + (li & 7) * 8) = *(const bf16x8*)(ysrc + li * 8);

  const u16_t* wsrc = Wt + ((size_t)kh * 64 + half * 32) * 8192;
  {
    const u16_t* g = wsrc + tid * 8;
    #pragma unroll
    for(int j = 0; j < 4; j++)
      gld_lds16(g + j * 2048, &wtile[0][j * 2048 + wid * 512]);
  }
  __syncthreads();

  int wm = wid >> 1, wn = wid & 1;
  f32x4 acc[2][4];
  #pragma unroll
  for(int m = 0; m < 2; m++)
    #pragma unroll
    for(int n = 0; n < 4; n++) acc[m][n] = (f32x4){0.f, 0.f, 0.f, 0.f};
  int arow0 = wm * 32 + l15;

  int qoff[2][4];
  #pragma unroll
  for(int ks = 0; ks < 2; ks++)
    #pragma unroll
    for(int nf = 0; nf < 4; nf++){
      int oc = wn * 64 + nf * 16 + l15;
      int byte = (oc << 7) | (((ks << 6) | (lgp << 4)) ^ ((oc & 7) << 4));
      qoff[ks][nf] = byte >> 1;
    }

  for(int kw = 0; kw < 32; kw++){
    int cur = kw & 1;
    if(kw < 31){
      const u16_t* g = wsrc + (size_t)(kw + 1) * 8192 + tid * 8;
      #pragma unroll
      for(int j = 0; j < 4; j++)
        gld_lds16(g + j * 2048, &wtile[cur ^ 1][j * 2048 + wid * 512]);
      asm volatile("s_waitcnt vmcnt(4)" ::: "memory");
    } else {
      asm volatile("s_waitcnt vmcnt(0)" ::: "memory");
    }
    __builtin_amdgcn_s_barrier();
    const u16_t* wt = wtile[cur];
    #pragma unroll
    for(int ks = 0; ks < 2; ks++){
      bf16x8 a0 = *(const bf16x8*)(strip + (arow0 + kw) * 72 + ks * 32 + lgp * 8);
      bf16x8 a1 = *(const bf16x8*)(strip + (arow0 + 16 + kw) * 72 + ks * 32 + lgp * 8);
      bf16x8 q0 = *(const bf16x8*)(wt + qoff[ks][0]);
      bf16x8 q1 = *(const bf16x8*)(wt + qoff[ks][1]);
      bf16x8 q2 = *(const bf16x8*)(wt + qoff[ks][2]);
      bf16x8 q3 = *(const bf16x8*)(wt + qoff[ks][3]);
      acc[0][0] = MFMA16(a0, q0, acc[0][0]);
      acc[0][1] = MFMA16(a0, q1, acc[0][1]);
      acc[0][2] = MFMA16(a0, q2, acc[0][2]);
      acc[0][3] = MFMA16(a0, q3, acc[0][3]);
      acc[1][0] = MFMA16(a1, q0, acc[1][0]);
      acc[1][1] = MFMA16(a1, q1, acc[1][1]);
      acc[1][2] = MFMA16(a1, q2, acc[1][2]);
      acc[1][3] = MFMA16(a1, q3, acc[1][3]);
    }
    asm volatile("s_waitcnt lgkmcnt(0)" ::: "memory");
    __builtin_amdgcn_s_barrier();
  }

  float* dst = part + ((size_t)khh * BT + (size_t)mt * 64) * 128;
  #pragma unroll
  for(int mf = 0; mf < 2; mf++)
    #pragma unroll
    for(int nf = 0; nf < 4; nf++)
      #pragma unroll
      for(int r = 0; r < 4; r++){
        int row = wm * 32 + mf * 16 + lgp * 4 + r;
        int col = wn * 64 + nf * 16 + l15;
        dst[row * 128 + col] = acc[mf][nf][r];
      }
}

// ====== fused GLU + attention (8 rows / WG, 512 blocks) + w2 tail on layer 2 ======
__global__ __launch_bounds__(256) void k_attn(const float* __restrict__ part,
    const float* __restrict__ convb, const float* __restrict__ ycur,
    const u16_t* __restrict__ eabf, const u16_t* __restrict__ eoT,
    const float* __restrict__ Wce, const float* __restrict__ bce,
    const float* __restrict__ Wec, const float* __restrict__ bec,
    float* __restrict__ ynext, u16_t* __restrict__ ybf,
    const float* __restrict__ dl1v, const float* __restrict__ W2,
    const float* __restrict__ b2, u16_t* __restrict__ y2bf,
    float* __restrict__ esum, int L){
  int row0 = blockIdx.x << 3;      // 8 rows per block, 512 blocks
  int b = row0 >> 9;
  int tid = threadIdx.x;
  int lane = tid & 63, w = tid >> 6;
  int l15 = lane & 15, lgp = lane >> 4;

  __shared__ float yml[8][68];
  __shared__ float pgS[8][68];
  __shared__ u16_t pgb[16][72];    // rows 8..15 zeroed (q>=8 lanes carry benign garbage)
  __shared__ float aof[4][64][17];
  __shared__ float aosm[8][68];
  __shared__ float reds[4][16];
  __shared__ float invt[8];

  // zero pgb rows 8..15 (cols 0..63 are all that qpg reads)
  for(int i = tid; i < 512; i += 256) pgb[8 + (i >> 6)][i & 63] = 0;

  // phase 0: GLU + residual (10 kw-split partials)
  for(int i = tid; i < 512; i += 256){
    int r = i >> 6, h = i & 63;
    int grow = row0 + r;
    float ca = convb[h], cb = convb[64 + h];
    #pragma unroll
    for(int pp = 0; pp < 10; pp++){
      int bpp = b + (pp >> 1) - 2;
      if(bpp >= 0 && bpp < NB){
        const float* p = part + ((size_t)pp * BT + grow) * 128;
        ca += p[h]; cb += p[64 + h];
      }
    }
    float sig = 1.f / (1.f + __expf(-cb));
    yml[r][h] = (ca * sig + ycur[(size_t)grow * 64 + h]) * SQH;
  }
  __syncthreads();
  // phase 0b: pg logits = yml @ Wce + bce (2 rows per 64-thread group)
  {
    int h = tid & 63, g = tid >> 6;
    float a0 = bce[h], a1 = a0;
    #pragma unroll 16
    for(int e = 0; e < 64; e++){
      float wv = Wce[e * 64 + h];
      a0 = fmaf(yml[g * 2 + 0][e], wv, a0);
      a1 = fmaf(yml[g * 2 + 1][e], wv, a1);
    }
    pgS[g * 2 + 0][h] = a0; pgS[g * 2 + 1][h] = a1;
  }
  __syncthreads();
  // phase 1: softmax over 64, normalized pg -> bf16 (8 rows, one pass)
  {
    int r = tid >> 5, j = tid & 31;
    float v1 = __expf(pgS[r][j]), v2 = __expf(pgS[r][j + 32]);
    float s = v1 + v2;
    s += __shfl_xor(s, 1); s += __shfl_xor(s, 2); s += __shfl_xor(s, 4);
    s += __shfl_xor(s, 8); s += __shfl_xor(s, 16);
    float inv = 1.f / s;
    pgb[r][j] = f2bf(v1 * inv); pgb[r][j + 32] = f2bf(v2 * inv);
  }
  __syncthreads();

  // phase 2: per-wave 256-s slice: S^T = mfma(ea, pg); P = exp; AV = mfma(eoT, P^T)
  bf16x8 qpg0 = *(const bf16x8*)&pgb[l15][lgp * 8];
  bf16x8 qpg1 = *(const bf16x8*)&pgb[l15][32 + lgp * 8];
  float sumacc = 0.f;
  f32x4 ao[4];
  #pragma unroll
  for(int et = 0; et < 4; et++) ao[et] = (f32x4){0.f, 0.f, 0.f, 0.f};
  const u16_t* eab = eabf + ((size_t)b * NS + w * 256) * 64;
  const u16_t* eob = eoT + (size_t)b * 64 * NS + w * 256;
  for(int sc = 0; sc < 8; sc++){
    int sb = sc * 32;
    const u16_t* ar = eab + (size_t)(sb + l15) * 64 + lgp * 8;
    bf16x8 a00 = *(const bf16x8*)ar;
    bf16x8 a01 = *(const bf16x8*)(ar + 32);
    bf16x8 a10 = *(const bf16x8*)(ar + 1024);
    bf16x8 a11 = *(const bf16x8*)(ar + 1024 + 32);
    f32x4 s0 = {0.f, 0.f, 0.f, 0.f}, s1 = {0.f, 0.f, 0.f, 0.f};
    s0 = MFMA16(a00, qpg0, s0); s0 = MFMA16(a01, qpg1, s0);
    s1 = MFMA16(a10, qpg0, s1); s1 = MFMA16(a11, qpg1, s1);
    float p00 = __expf(s0[0]), p01 = __expf(s0[1]), p02 = __expf(s0[2]), p03 = __expf(s0[3]);
    float p10 = __expf(s1[0]), p11 = __expf(s1[1]), p12 = __expf(s1[2]), p13 = __expf(s1[3]);
    sumacc += (p00 + p01) + (p02 + p03) + (p10 + p11) + (p12 + p13);
    u32_t A0, B0, A1, B1;
    asm("v_cvt_pk_bf16_f32 %0, %1, %2" : "=v"(A0) : "v"(p00), "v"(p01));
    asm("v_cvt_pk_bf16_f32 %0, %1, %2" : "=v"(B0) : "v"(p02), "v"(p03));
    asm("v_cvt_pk_bf16_f32 %0, %1, %2" : "=v"(A1) : "v"(p10), "v"(p11));
    asm("v_cvt_pk_bf16_f32 %0, %1, %2" : "=v"(B1) : "v"(p12), "v"(p13));
    int src0 = l15 + ((lgp & 1) << 5);
    int src1 = src0 + 16;
    u32_t w0a = (u32_t)__shfl((int)A0, src0, 64), w0b = (u32_t)__shfl((int)A1, src0, 64);
    u32_t w1a = (u32_t)__shfl((int)B0, src0, 64), w1b = (u32_t)__shfl((int)B1, src0, 64);
    u32_t w2a = (u32_t)__shfl((int)A0, src1, 64), w2b = (u32_t)__shfl((int)A1, src1, 64);
    u32_t w3a = (u32_t)__shfl((int)B0, src1, 64), w3b = (u32_t)__shfl((int)B1, src1, 64);
    bool hi = lgp >= 2;
    union { u32_t u[4]; bf16x8 v; } bav;
    bav.u[0] = hi ? w0b : w0a; bav.u[1] = hi ? w1b : w1a;
    bav.u[2] = hi ? w2b : w2a; bav.u[3] = hi ? w3b : w3a;
    #pragma unroll
    for(int et = 0; et < 4; et++){
      const u16_t* er = eob + (size_t)(et * 16 + l15) * NS + sb + lgp * 8;
      bf16x8 ae = *(const bf16x8*)er;
      ao[et] = MFMA16(ae, bav.v, ao[et]);
    }
  }
  sumacc += __shfl_xor(sumacc, 16);
  sumacc += __shfl_xor(sumacc, 32);
  if(lane < 16) reds[w][l15] = sumacc;
  #pragma unroll
  for(int et = 0; et < 4; et++)
    #pragma unroll
    for(int r = 0; r < 4; r++)
      aof[w][et * 16 + lgp * 4 + r][l15] = ao[et][r];
  __syncthreads();
  if(tid < 8) invt[tid] = ATTN_SCALE / (reds[0][tid] + reds[1][tid] + reds[2][tid] + reds[3][tid]);
  __syncthreads();
  // phase 3: sum wave partials, scale, transpose to [t][e] (t < 8)
  for(int i = tid; i < 512; i += 256){
    int e = i >> 3, t = i & 7;
    aosm[t][e] = (aof[0][e][t] + aof[1][e][t] + aof[2][e][t] + aof[3][e][t]) * invt[t];
  }
  __syncthreads();
  // phase 4: y logits = aosm @ Wec + bec
  {
    int h = tid & 63, g = tid >> 6;
    float a0 = bec[h], a1 = a0;
    #pragma unroll 16
    for(int e = 0; e < 64; e++){
      float wv = Wec[e * 64 + h];
      a0 = fmaf(aosm[g * 2 + 0][e], wv, a0);
      a1 = fmaf(aosm[g * 2 + 1][e], wv, a1);
    }
    pgS[g * 2 + 0][h] = a0; pgS[g * 2 + 1][h] = a1;
  }
  __syncthreads();
  // phase 5: softmax over 64; store (L<2) or stash for w2 tail (L==2)
  {
    int r = tid >> 5, j = tid & 31;
    float v1 = __expf(pgS[r][j]), v2 = __expf(pgS[r][j + 32]);
    float s = v1 + v2;
    s += __shfl_xor(s, 1); s += __shfl_xor(s, 2); s += __shfl_xor(s, 4);
    s += __shfl_xor(s, 8); s += __shfl_xor(s, 16);
    float inv = 1.f / s;
    float o1 = v1 * inv, o2 = v2 * inv;
    if(L < 2){
      int grow = row0 + r;
      ynext[(size_t)grow * 64 + j] = o1;
      ynext[(size_t)grow * 64 + j + 32] = o2;
      size_t yb = ((size_t)(grow >> 9) * 576 + (grow & 511) + 31) * 64;
      ybf[yb + j] = f2bf(o1);
      ybf[yb + j + 32] = f2bf(o2);
    } else {
      yml[r][j] = o1;
      yml[r][j + 32] = o2;
    }
  }
  if(L == 2){
    __syncthreads();
    // w2 tail: x = (y + dl1)*SQ ; y2 = relu(x@W2+b2) -> bf16 ; zero esum
    for(int i = tid; i < 512; i += 256){
      int r = i >> 6, h = i & 63;
      pgS[r][h] = (yml[r][h] + dl1v[(size_t)(row0 + r) * 64 + h]) * SQH;
    }
    __syncthreads();
    int h = tid & 63, g = tid >> 6;
    float a0 = b2[h], a1 = a0;
    #pragma unroll 16
    for(int e = 0; e < 64; e++){
      float wv = W2[e * 64 + h];
      a0 = fmaf(pgS[g * 2 + 0][e], wv, a0);
      a1 = fmaf(pgS[g * 2 + 1][e], wv, a1);
    }
    y2bf[(size_t)(row0 + g * 2 + 0) * 64 + h] = f2bf(fmaxf(a0, 0.f));
    y2bf[(size_t)(row0 + g * 2 + 1) * 64 + h] = f2bf(fmaxf(a1, 0.f));
    if(tid < 8) esum[row0 + tid] = 0.f;
  }
}

// ================= V-GEMM pass A (M-tile 64) =================
__global__ __launch_bounds__(256) void k_va(const u16_t* __restrict__ y2bf,
    const u16_t* __restrict__ W3t, const float* __restrict__ b3, float* __restrict__ esum){
  int m0 = blockIdx.x << 6, ns = blockIdx.y;
  int tid = threadIdx.x, lane = tid & 63, w = tid >> 6;
  int l15 = lane & 15, lgp = lane >> 4;
  bf16x8 a[4][2];
  #pragma unroll
  for(int mg = 0; mg < 4; mg++){
    const u16_t* ar = y2bf + ((size_t)(m0 + mg * 16 + l15) << 6) + lgp * 8;
    a[mg][0] = *(const bf16x8*)ar;
    a[mg][1] = *(const bf16x8*)(ar + 32);
  }
  float sums[4][4];
  #pragma unroll
  for(int mg = 0; mg < 4; mg++)
    #pragma unroll
    for(int r = 0; r < 4; r++) sums[mg][r] = 0.f;

  int nb0 = ns * 1600 + w * 400;
  for(int fi = 0; fi < 25; fi++){
    int n = nb0 + fi * 16 + l15;
    const u16_t* bp2 = W3t + ((size_t)n << 6) + lgp * 8;
    bf16x8 q0 = *(const bf16x8*)bp2;
    bf16x8 q1 = *(const bf16x8*)(bp2 + 32);
    float bias = b3[n];
    #pragma unroll
    for(int mg = 0; mg < 4; mg++){
      f32x4 acc = {0.f, 0.f, 0.f, 0.f};
      acc = MFMA16(a[mg][0], q0, acc);
      acc = MFMA16(a[mg][1], q1, acc);
      #pragma unroll
      for(int r = 0; r < 4; r++){
        float z = fmaxf(acc[r] + bias, 0.f);
        sums[mg][r] += __expf(z);
      }
    }
  }
  #pragma unroll
  for(int mg = 0; mg < 4; mg++)
    #pragma unroll
    for(int r = 0; r < 4; r++){
      float v = sums[mg][r];
      v += __shfl_xor(v, 1); v += __shfl_xor(v, 2);
      v += __shfl_xor(v, 4); v += __shfl_xor(v, 8);
      if(l15 == 0) atomicAdd(&esum[m0 + mg * 16 + lgp * 4 + r], v);
    }
}

// ================= V-GEMM pass B (M-tile 64, coalesced obuf stores) ===============
__global__ __launch_bounds__(256) void k_vb(const u16_t* __restrict__ y2bf,
    const u16_t* __restrict__ W3t, const float* __restrict__ b3,
    const float* __restrict__ esum, float* __restrict__ out){
  int m0 = blockIdx.x << 6, ns = blockIdx.y;
  int tid = threadIdx.x, lane = tid & 63, w = tid >> 6;
  int l15 = lane & 15, lgp = lane >> 4;
  __shared__ float obuf[64][84];
  bf16x8 a[4][2];
  #pragma unroll
  for(int mg = 0; mg < 4; mg++){
    const u16_t* ar = y2bf + ((size_t)(m0 + mg * 16 + l15) << 6) + lgp * 8;
    a[mg][0] = *(const bf16x8*)ar;
    a[mg][1] = *(const bf16x8*)(ar + 32);
  }
  float invs[4][4];
  #pragma unroll
  for(int mg = 0; mg < 4; mg++)
    #pragma unroll
    for(int r = 0; r < 4; r++) invs[mg][r] = 1.f / esum[m0 + mg * 16 + lgp * 4 + r];

  int cb0 = ns * 1600;
  for(int si = 0; si < 25; si++){
    int cb = cb0 + si * 64;
    int n = cb + w * 16 + l15;
    const u16_t* bp2 = W3t + ((size_t)n << 6) + lgp * 8;
    bf16x8 q0 = *(const bf16x8*)bp2;
    bf16x8 q1 = *(const bf16x8*)(bp2 + 32);
    float bias = b3[n];
    #pragma unroll
    for(int mg = 0; mg < 4; mg++){
      f32x4 acc = {0.f, 0.f, 0.f, 0.f};
      acc = MFMA16(a[mg][0], q0, acc);
      acc = MFMA16(a[mg][1], q1, acc);
      #pragma unroll
      for(int r = 0; r < 4; r++){
        float z = fmaxf(acc[r] + bias, 0.f);
        obuf[mg * 16 + lgp * 4 + r][w * 16 + l15] = __expf(z) * invs[mg][r];
      }
    }
    __syncthreads();
    #pragma unroll
    for(int p = 0; p < 4; p++){
      int row = p * 16 + (tid >> 4);
      float4 v = *(const float4*)&obuf[row][(tid & 15) * 4];
      *(float4*)&out[(size_t)(m0 + row) * NV + cb + (tid & 15) * 4] = v;
    }
    __syncthreads();
  }
}

extern "C" void kernel_launch(void* const* d_in, const int* in_sizes, int n_in,
                              void* d_out, int out_size, void* d_ws, size_t ws_size,
                              hipStream_t stream){
  const float* input_x = (const float*)d_in[0];
  const float* enc_out = (const float*)d_in[1];
  const float* enc_att = (const float*)d_in[2];
  const float* W1    = (const float*)d_in[3];
  const float* b1    = (const float*)d_in[4];
  const float* convW = (const float*)d_in[5];
  const float* convb = (const float*)d_in[6];
  const float* Wce   = (const float*)d_in[7];
  const float* bce   = (const float*)d_in[8];
  const float* Wec   = (const float*)d_in[9];
  const float* bec   = (const float*)d_in[10];
  const float* W2    = (const float*)d_in[11];
  const float* b2    = (const float*)d_in[12];
  const float* W3    = (const float*)d_in[13];
  const float* b3    = (const float*)d_in[14];

  char* ws = (char*)d_ws;
  u16_t* Wt    = (u16_t*)(ws);                 // 5,242,880 B
  u16_t* W3t   = (u16_t*)(ws + 5242880);       // 4,096,000 B
  float* dl1v  = (float*)(ws + 9338880);       // 1,048,576 B
  float* yB    = (float*)(ws + 10387456);      // 1,048,576 B
  u16_t* ybf   = (u16_t*)(ws + 11436032);      //   589,824 B
  float* part  = (float*)(ws + 12025856);      // 20,971,520 B (10 partials)
  u16_t* y2bf  = (u16_t*)(ws + 32997376);      //   524,288 B
  float* esum  = (float*)(ws + 33521664);      //    16,384 B
  u16_t* eabf  = (u16_t*)(ws + 33538048);      // 1,048,576 B
  u16_t* eoT   = (u16_t*)(ws + 34586624);      // 1,048,576 B
  float* outp  = (float*)d_out;

  k_prep<<<dim3(1725), dim3(256), 0, stream>>>(input_x, enc_out, enc_att, W1, b1,
                                               convW, W3, Wt, W3t, dl1v, ybf, eabf, eoT);

  const float* ycur = dl1v;
  for(int it = 0; it < 3; it++){
    k_conv<<<dim3(64, 10), dim3(256), 0, stream>>>(ybf, Wt, part);
    k_attn<<<dim3(512), dim3(256), 0, stream>>>(part, convb, ycur, eabf, eoT,
                                                Wce, bce, Wec, bec, yB, ybf,
                                                dl1v, W2, b2, y2bf, esum, it);
    ycur = yB;
  }

  k_va<<<dim3(64, 20), dim3(256), 0, stream>>>(y2bf, W3t, b3, esum);
  k_vb<<<dim3(64, 20), dim3(256), 0, stream>>>(y2bf, W3t, b3, esum, outp);
}